// Round 1
// baseline (145.377 us; speedup 1.0000x reference)
//
#include <hip/hip_runtime.h>

#define N_NODES 50000
#define N_EDGES 800000
#define IN_CH   256
#define OUT_C H_unused 0
#undef OUT_C
#define OUT_CH  128

#define NB        391          // coarse buckets of 128 nodes: ceil(50000/128)
#define CAP       3072         // record capacity per bucket (mean 2048, sd ~45)
#define L1_CHUNK  2048
#define GBM       64
#define NGEMM     ((N_NODES + GBM - 1) / GBM)             // 782 gemm blocks

typedef __attribute__((ext_vector_type(8))) short short8;   // 8 bf16 (4 VGPRs)
typedef __attribute__((ext_vector_type(4))) float f32x4;

__device__ __forceinline__ short f2bf(float f) {
    unsigned u = __float_as_uint(f);
    unsigned r = (u + 0x7fffu + ((u >> 16) & 1u)) >> 16;    // RNE
    return (short)r;
}

// ------------- one-time: W fp32 -> bf16, zero bcnt -----------------------
__global__ __launch_bounds__(256) void convert_w(const float* __restrict__ W,
                                                 short* __restrict__ Wbf,
                                                 int* __restrict__ bcnt) {
    int t = blockIdx.x * 256 + threadIdx.x;       // 4096 threads, 8 floats each
    const float* wp = W + t * 8;
    float4 v0 = ((const float4*)wp)[0];
    float4 v1 = ((const float4*)wp)[1];
    short8 s;
    s[0]=f2bf(v0.x); s[1]=f2bf(v0.y); s[2]=f2bf(v0.z); s[3]=f2bf(v0.w);
    s[4]=f2bf(v1.x); s[5]=f2bf(v1.y); s[6]=f2bf(v1.z); s[7]=f2bf(v1.w);
    *(short8*)&Wbf[t * 8] = s;
    if (t < NB) bcnt[t] = 0;
}

// ---------------- fused: MFMA GEMM (blocks 0..781) + edge bucketing ------
// GEMM tile 64x128: 782 blocks -> ~4.6 blocks/CU so the per-iter HBM
// A-load latency hides across blocks (128-tile gave only 1.5 blocks/CU).
#define GBK 32
#define LDK 40   // padded row length (bf16 elems); 80B stride keeps 16B align
__global__ __launch_bounds__(256) void gemm_bucket(const float* __restrict__ x,
                                                   const short* __restrict__ Wbf,
                                                   const float* __restrict__ bias,
                                                   short* __restrict__ linbf,
                                                   const int* __restrict__ src,
                                                   const int* __restrict__ dst,
                                                   int* __restrict__ bcnt,
                                                   unsigned* __restrict__ rec) {
    __shared__ __align__(16) char smem[15360];
    const int tid = threadIdx.x;

    if (blockIdx.x < NGEMM) {
        // ================= GEMM part =================
        short* As = (short*)smem;            // 5120 B:  [m][k] tile (64 x 32)
        short* Bs = (short*)(smem + 5120);   // 10240 B: [n][k] tile (128 x 32)

        const int m0  = blockIdx.x * GBM;
        const int w    = tid >> 6;
        const int lane = tid & 63;
        const int lm   = lane & 15;
        const int lq   = lane >> 4;
        const int wrow = (w >> 1) * 32;
        const int wcol = (w & 1) * 64;

        f32x4 acc[2][4];
#pragma unroll
        for (int i = 0; i < 2; ++i)
#pragma unroll
            for (int j = 0; j < 4; ++j) acc[i][j] = (f32x4)(0.0f);

        const int arow = tid >> 2;        // A staging row (0..63)
        const int aq   = tid & 3;         // which 8-k group
        const int brow = tid >> 1;        // B staging row (0..127)
        const int bhalf = tid & 1;        // which 16-k half

        for (int k0 = 0; k0 < IN_CH; k0 += GBK) {
            // stage A: 64 rows x 32 k, fp32 -> bf16 (32 B / thread)
            {
                float4 v0 = make_float4(0.f,0.f,0.f,0.f), v1 = v0;
                if (m0 + arow < N_NODES) {
                    const float* xp = x + (size_t)(m0 + arow) * IN_CH + k0 + aq * 8;
                    v0 = ((const float4*)xp)[0];
                    v1 = ((const float4*)xp)[1];
                }
                short8 s;
                s[0]=f2bf(v0.x); s[1]=f2bf(v0.y); s[2]=f2bf(v0.z); s[3]=f2bf(v0.w);
                s[4]=f2bf(v1.x); s[5]=f2bf(v1.y); s[6]=f2bf(v1.z); s[7]=f2bf(v1.w);
                *(short8*)&As[arow * LDK + aq * 8] = s;
            }
            // stage B: 128 n x 32 k (pre-converted bf16, straight copy)
            {
                const short* wp = Wbf + (size_t)brow * IN_CH + k0 + bhalf * 16;
                *(short8*)&Bs[brow * LDK + bhalf * 16]     = ((const short8*)wp)[0];
                *(short8*)&Bs[brow * LDK + bhalf * 16 + 8] = ((const short8*)wp)[1];
            }
            __syncthreads();

            short8 af[2], bfr[4];
#pragma unroll
            for (int rt = 0; rt < 2; ++rt)
                af[rt] = *(const short8*)&As[(wrow + rt * 16 + lm) * LDK + lq * 8];
#pragma unroll
            for (int ct = 0; ct < 4; ++ct)
                bfr[ct] = *(const short8*)&Bs[(wcol + ct * 16 + lm) * LDK + lq * 8];
#pragma unroll
            for (int rt = 0; rt < 2; ++rt)
#pragma unroll
                for (int ct = 0; ct < 4; ++ct)
                    acc[rt][ct] = __builtin_amdgcn_mfma_f32_16x16x32_bf16(
                        af[rt], bfr[ct], acc[rt][ct], 0, 0, 0);
            __syncthreads();
        }

        // epilogue: D row = lq*4 + r, col = lm
#pragma unroll
        for (int ct = 0; ct < 4; ++ct) {
            int gcol = wcol + ct * 16 + lm;
            float bv = bias[gcol];
#pragma unroll
            for (int rt = 0; rt < 2; ++rt) {
#pragma unroll
                for (int r = 0; r < 4; ++r) {
                    int grow = m0 + wrow + rt * 16 + lq * 4 + r;
                    if (grow < N_NODES)
                        linbf[(size_t)grow * OUT_CH + gcol] = f2bf(acc[rt][ct][r] + bv);
                }
            }
        }
    } else {
        // ================= bucket-scatter part =================
        // packed record: src (16b) | (dst&127)<<16 (7b) | (dst>>7)<<23 (9b)
        int* lhist       = (int*)smem;             // 1564 B
        int* lscan       = (int*)(smem + 1568);    // 1564 B
        int* lbase       = (int*)(smem + 3136);    // 1564 B
        unsigned* staged = (unsigned*)(smem + 4704); // 8192 B

        const int blk = blockIdx.x - NGEMM;
        const int e0  = blk * L1_CHUNK;
        const int total = min(L1_CHUNK, N_EDGES - e0);

        for (int i = tid; i < NB; i += 256) lhist[i] = 0;
        __syncthreads();

        unsigned mypk[8];
        int myr[8];
        int myb[8];
#pragma unroll
        for (int j = 0; j < 8; ++j) {
            int i = tid + j * 256;
            myb[j] = -1;
            if (i < total) {
                unsigned d = (unsigned)dst[e0 + i];
                unsigned s = (unsigned)src[e0 + i];
                int b = (int)(d >> 7);
                myb[j] = b;
                mypk[j] = s | ((d & 127u) << 16) | ((unsigned)b << 23);
                myr[j] = atomicAdd(&lhist[b], 1);
            }
        }
        __syncthreads();

        // exclusive scan lhist -> lscan (wave 0, 7 chunks of 64)
        if (tid < 64) {
            int carry = 0;
            for (int c = 0; c < NB; c += 64) {
                int idx = c + tid;
                int v = (idx < NB) ? lhist[idx] : 0;
                int incl = v;
#pragma unroll
                for (int s = 1; s < 64; s <<= 1) {
                    int t = __shfl_up(incl, s, 64);
                    if (tid >= s) incl += t;
                }
                if (idx < NB) lscan[idx] = carry + incl - v;
                carry += __shfl(incl, 63, 64);
            }
        }
        __syncthreads();

        // reserve global space (one atomic per nonempty bucket) + stage locally
        for (int bkt = tid; bkt < NB; bkt += 256) {
            int c = lhist[bkt];
            lbase[bkt] = c ? atomicAdd(&bcnt[bkt], c) : 0;
        }
#pragma unroll
        for (int j = 0; j < 8; ++j) {
            if (myb[j] >= 0)
                staged[lscan[myb[j]] + myr[j]] = mypk[j];
        }
        __syncthreads();

        // write out: bucket-grouped runs -> mostly-contiguous global stores
        for (int p = tid; p < total; p += 256) {
            unsigned r = staged[p];
            int b = (int)(r >> 23);
            int gpos = lbase[b] + (p - lscan[b]);
            if (gpos < CAP)
                rec[(size_t)b * CAP + gpos] = r;
        }
    }
}

// ---------- fine gather v2: quarter-bucket blocks (32 nodes, 256 thr) ----
// 391 x 1024-thread blocks was an occupancy cliff: 16-wave blocks need
// VGPR<=64 for 2 blocks/CU; past that it's 1 block/CU = 16 waves and a
// 1.53-round grid (half the machine idle in round 2). 256-thread blocks
// degrade gracefully with VGPR count (up to 8 blocks/CU = 32 waves) and
// 1564 blocks give 1.15x (vs 1.31x) per-CU work quantization.
// Records are streamed twice from global (L2-resident, 3.2 MB total)
// instead of staged in LDS: LDS drops 20 KB -> 2.4 KB.
#define FG_THR 256
#define QCAP   1024            // quarter capacity: mean 512, sd ~23 -> 22 sigma
__global__ __launch_bounds__(FG_THR) void fine_gather(const int* __restrict__ bcnt,
                                                      const unsigned* __restrict__ rec,
                                                      const short* __restrict__ linbf,
                                                      float* __restrict__ out) {
    __shared__ unsigned short ssrc[QCAP];   // 2048 B
    __shared__ int fh[32], fo[32], fc[32];

    const int tid = threadIdx.x;
    const int b   = blockIdx.x >> 2;        // coarse bucket
    const int q   = blockIdx.x & 3;         // quarter within bucket
    const int lo  = q * 32;                 // first fine node of this quarter
    const int cnt = min(bcnt[b], CAP);
    const unsigned* rp = rec + (size_t)b * CAP;

    if (tid < 32) fh[tid] = 0;
    __syncthreads();

    // pass 1: filter-histogram this quarter's fine nodes
    for (int i = tid; i < cnt; i += FG_THR) {
        int f = (int)((rp[i] >> 16) & 127u) - lo;
        if ((unsigned)f < 32u) atomicAdd(&fh[f], 1);
    }
    __syncthreads();

    // exclusive scan of 32 counters (lanes 0..31 of wave 0)
    if (tid < 32) {
        int v = fh[tid], incl = v;
#pragma unroll
        for (int s = 1; s < 32; s <<= 1) {
            int t = __shfl_up(incl, s, 32);
            if (tid >= s) incl += t;
        }
        fo[tid] = incl - v;
        fc[tid] = incl - v;
    }
    __syncthreads();

    // pass 2: filter-scatter srcs into sorted LDS order
    for (int i = tid; i < cnt; i += FG_THR) {
        unsigned r = rp[i];
        int f = (int)((r >> 16) & 127u) - lo;
        if ((unsigned)f < 32u) {
            int p = atomicAdd(&fc[f], 1);
            if (p < QCAP) ssrc[p] = (unsigned short)(r & 0xffffu);
        }
    }
    __syncthreads();

    // gather phase: 16 lanes per node, 16 nodes in flight, 2 rounds
    const int l = tid & 15;
#pragma unroll 1
    for (int g = 0; g < 2; ++g) {
        int fn = g * 16 + (tid >> 4);          // local node 0..31
        int n = b * 128 + lo + fn;
        if (n >= N_NODES) continue;
        const int beg = fo[fn];
        const int deg = fh[fn];
        const int end = beg + deg;

        float a[8];
#pragma unroll
        for (int j = 0; j < 8; ++j) a[j] = 0.0f;

        int i = beg;
        for (; i + 3 < end; i += 4) {
            uint4 u[4];
#pragma unroll
            for (int e = 0; e < 4; ++e) {
                int s = ssrc[i + e];
                u[e] = *(const uint4*)&linbf[(size_t)s * OUT_CH + l * 8];
            }
#pragma unroll
            for (int e = 0; e < 4; ++e) {
                const unsigned* p = (const unsigned*)&u[e];
#pragma unroll
                for (int j = 0; j < 4; ++j) {
                    a[2*j]   += __uint_as_float(p[j] << 16);
                    a[2*j+1] += __uint_as_float(p[j] & 0xffff0000u);
                }
            }
        }
        for (; i < end; ++i) {
            int s = ssrc[i];
            uint4 u0 = *(const uint4*)&linbf[(size_t)s * OUT_CH + l * 8];
            const unsigned* p0 = (const unsigned*)&u0;
#pragma unroll
            for (int j = 0; j < 4; ++j) {
                a[2*j]   += __uint_as_float(p0[j] << 16);
                a[2*j+1] += __uint_as_float(p0[j] & 0xffff0000u);
            }
        }
        float inv = 1.0f / (float)(deg > 1 ? deg : 1);
        float4 o0, o1;
        o0.x = a[0]*inv; o0.y = a[1]*inv; o0.z = a[2]*inv; o0.w = a[3]*inv;
        o1.x = a[4]*inv; o1.y = a[5]*inv; o1.z = a[6]*inv; o1.w = a[7]*inv;
        float* op = &out[(size_t)n * OUT_CH + l * 8];
        ((float4*)op)[0] = o0;
        ((float4*)op)[1] = o1;
    }
}

extern "C" void kernel_launch(void* const* d_in, const int* in_sizes, int n_in,
                              void* d_out, int out_size, void* d_ws, size_t ws_size,
                              hipStream_t stream) {
    const float* x  = (const float*)d_in[0];
    const int*   ei = (const int*)d_in[1];     // [2][E]: src then dst
    const float* W  = (const float*)d_in[2];
    const float* b  = (const float*)d_in[3];
    float* out = (float*)d_out;

    const int* src = ei;
    const int* dst = ei + N_EDGES;

    // workspace: linbf 12.8MB | Wbf 64KB | rec 4.8MB | bcnt
    char* ws = (char*)d_ws;
    short*    linbf = (short*)ws;    ws += ((size_t)N_NODES * OUT_CH * sizeof(short) + 255) & ~255ull;
    short*    Wbf   = (short*)ws;    ws += ((size_t)IN_CH * OUT_CH * sizeof(short) + 255) & ~255ull;
    unsigned* rec   = (unsigned*)ws; ws += ((size_t)NB * CAP * sizeof(unsigned) + 255) & ~255ull;
    int*      bcnt  = (int*)ws;

    convert_w<<<16, 256, 0, stream>>>(W, Wbf, bcnt);
    gemm_bucket<<<NGEMM + NB, 256, 0, stream>>>(x, Wbf, b, linbf, src, dst, bcnt, rec);
    fine_gather<<<NB * 4, FG_THR, 0, stream>>>(bcnt, rec, linbf, out);
}